// Round 8
// baseline (2906.111 us; speedup 1.0000x reference)
//
#include <hip/hip_runtime.h>
#include <hip/hip_bf16.h>
#include <float.h>

#define NEG_SLOPE 0.01f

__device__ __forceinline__ float leaky(float x){ return x >= 0.0f ? x : NEG_SLOPE * x; }

// ---------------- transpose a batch of 64x64 matrices: [o][d] -> [d][o] ----------------
__global__ void k_transpose(const float* __restrict__ src, float* __restrict__ dst){
    int m = blockIdx.x;
    const float* s = src + (size_t)m * 4096;
    float* d = dst + (size_t)m * 4096;
    for (int t = threadIdx.x; t < 4096; t += blockDim.x){
        int o = t >> 6, dd = t & 63;
        d[dd * 64 + o] = s[t];
    }
}

// ---------------- first conv: 3 -> 64 ----------------
__global__ void k_conv0(const float* __restrict__ xyz, const float* __restrict__ w0,
                        float* __restrict__ out, int n){
    int t = blockIdx.x * blockDim.x + threadIdx.x;
    int nn = t % n;
    int rest = t / n;
    int o = rest & 63;
    int b = rest >> 6;
    const float* X = xyz + (size_t)b * 3 * n;
    float x = X[nn], y = X[n + nn], z = X[2 * n + nn];
    out[((size_t)b * 64 + o) * n + nn] = w0[o*3] * x + w0[o*3+1] * y + w0[o*3+2] * z;
}

// ---------------- kNN: for each query, indices of 8 nearest refs ----------------
#define KNN_CHUNK 1024
#define BKNN 64

#define KNN_INS(bdX, biX) { bool c = cd < bdX; float tf = bdX; int ti = biX; \
    bdX = c ? cd : bdX; biX = c ? ci : biX; cd = c ? tf : cd; ci = c ? ti : ci; }

__global__ void __launch_bounds__(BKNN, 1)
k_knn(const float* __restrict__ q, const float* __restrict__ ref,
      int M, int Nr, int* __restrict__ idx_out){
    __shared__ float4 sref[KNN_CHUNK];
    int b = blockIdx.y;
    int m = blockIdx.x * BKNN + threadIdx.x;
    const float* Q = q + (size_t)b * 3 * M;
    const float* R = ref + (size_t)b * 3 * Nr;
    bool valid = (m < M);
    float qx = 0.f, qy = 0.f, qz = 0.f, qq = 0.f;
    if (valid){
        qx = Q[m]; qy = Q[M + m]; qz = Q[2 * M + m];
        qq = qx*qx + qy*qy + qz*qz;
    }
    float bd0 = FLT_MAX, bd1 = FLT_MAX, bd2 = FLT_MAX, bd3 = FLT_MAX;
    float bd4 = FLT_MAX, bd5 = FLT_MAX, bd6 = FLT_MAX, bd7 = FLT_MAX;
    int bi0 = 0, bi1 = 0, bi2 = 0, bi3 = 0, bi4 = 0, bi5 = 0, bi6 = 0, bi7 = 0;

    for (int base = 0; base < Nr; base += KNN_CHUNK){
        int jmax = min(KNN_CHUNK, Nr - base);
        for (int j = threadIdx.x; j < jmax; j += BKNN){
            float rx = R[base + j], ry = R[Nr + base + j], rz = R[2 * Nr + base + j];
            sref[j] = make_float4(rx, ry, rz, rx*rx + ry*ry + rz*rz);
        }
        __syncthreads();
        for (int j = 0; j < jmax; ++j){
            float4 r = sref[j];
            float dot = qx * r.x + qy * r.y + qz * r.z;
            float d = qq + r.w - 2.0f * dot;
            if (d < bd7){
                // ascending-index scan + strict '<' => lowest index wins ties (matches lax.top_k)
                float cd = d; int ci = base + j;
                KNN_INS(bd0, bi0); KNN_INS(bd1, bi1); KNN_INS(bd2, bi2); KNN_INS(bd3, bi3);
                KNN_INS(bd4, bi4); KNN_INS(bd5, bi5); KNN_INS(bd6, bi6); KNN_INS(bd7, bi7);
            }
        }
        __syncthreads();
    }
    if (valid){
        int* o = idx_out + ((size_t)b * M + m) * 8;
        o[0] = bi0; o[1] = bi1; o[2] = bi2; o[3] = bi3;
        o[4] = bi4; o[5] = bi5; o[6] = bi6; o[7] = bi7;
    }
}

// ---------------- farthest point sampling ----------------
// DPP reduction on the VALU; candidate packed as (float_bits(dist)<<32)|~idx
// for exact single-cmp tie-breaks; winner coords ride the DPP selects.
// r7: per-active-CU VALU busy ~69% => issue-bound; P=16 state (~80 floats)
// exceeded the 60-VGPR allocation (spill stalls). New shape: T=512 (8 waves,
// 2/SIMD) x P=8 -> ~58 live VGPRs (fits), half the per-wave issue work, and
// wave interleave hides DPP/barrier/LDS latency.

template<int CTRL>
__device__ __forceinline__ void dpp_step(unsigned long long &bp, float &x, float &y, float &z){
    unsigned h = (unsigned)(bp >> 32), l = (unsigned)bp;
    unsigned th = (unsigned)__builtin_amdgcn_update_dpp(0, (int)h, CTRL, 0xF, 0xF, true);
    unsigned tl = (unsigned)__builtin_amdgcn_update_dpp(0, (int)l, CTRL, 0xF, 0xF, true);
    float tx = __int_as_float(__builtin_amdgcn_update_dpp(0, __float_as_int(x), CTRL, 0xF, 0xF, true));
    float ty = __int_as_float(__builtin_amdgcn_update_dpp(0, __float_as_int(y), CTRL, 0xF, 0xF, true));
    float tz = __int_as_float(__builtin_amdgcn_update_dpp(0, __float_as_int(z), CTRL, 0xF, 0xF, true));
    unsigned long long tp = ((unsigned long long)th << 32) | tl;
    bool c = tp > bp;
    bp = c ? tp : bp; x = c ? tx : x; y = c ? ty : y; z = c ? tz : z;
}
// after these 6 steps lane 63 holds the wave's max (with coords)
#define DPP_REDUCE(bp, bx, by, bz) \
    dpp_step<0x111>(bp, bx, by, bz); \
    dpp_step<0x112>(bp, bx, by, bz); \
    dpp_step<0x114>(bp, bx, by, bz); \
    dpp_step<0x118>(bp, bx, by, bz); \
    dpp_step<0x142>(bp, bx, by, bz); \
    dpp_step<0x143>(bp, bx, by, bz);

#define FPS_DECL(i) float px##i, py##i, pz##i, ds##i; unsigned nti##i;
#define FPS_LOAD(i) { int gi = tid + (i) * T; px##i = X[gi]; py##i = X[N + gi]; \
                      pz##i = X[2 * N + gi]; ds##i = 1e10f; nti##i = ~(unsigned)gi; }
#define FPS_PIN(i) asm volatile("" : "+v"(px##i), "+v"(py##i), "+v"(pz##i));
// dist >= 0 always => float bit pattern order == float order; ~gi larger => gi smaller,
// so u64 max reproduces (dist >, tie: idx <) exactly.
#define FPS_UPD(i) { float dx = px##i - lx, dy = py##i - ly, dz = pz##i - lz; \
    float d = dx*dx + dy*dy + dz*dz; \
    float nd = fminf(ds##i, d); ds##i = nd; \
    unsigned long long cp = ((unsigned long long)__float_as_uint(nd) << 32) | nti##i; \
    bool c = cp > bp; \
    bp = c ? cp : bp; bx = c ? px##i : bx; by = c ? py##i : by; bz = c ? pz##i : bz; }

#define RPT16(M) M(0) M(1) M(2) M(3) M(4) M(5) M(6) M(7) \
                 M(8) M(9) M(10) M(11) M(12) M(13) M(14) M(15)
#define RPT8(M) M(0) M(1) M(2) M(3) M(4) M(5) M(6) M(7)
#define RPT4(M) M(0) M(1) M(2) M(3)

// multi-wave: one barrier/iter, per-wave winners (with coords) combined via LDS
#define FPS_BODY_MW(RPT, N_P, NP_P, T_P, NW) \
    constexpr int N = N_P, NPOINT = NP_P, T = T_P; \
    const int b = blockIdx.x; \
    const float* X = xyz + (size_t)b * 3 * N; \
    int tid = threadIdx.x; \
    RPT(FPS_DECL) RPT(FPS_LOAD) RPT(FPS_PIN) \
    __shared__ float4 sA[2][NW]; \
    __shared__ unsigned sB[2][NW]; \
    if (tid == 0) sidx[(size_t)b * NPOINT] = 0; \
    float lx = X[0], ly = X[N], lz = X[2 * N]; \
    for (int i = 1; i < NPOINT; ++i){ \
        unsigned long long bp = 0; float bx = 0.f, by = 0.f, bz = 0.f; \
        RPT(FPS_UPD) \
        DPP_REDUCE(bp, bx, by, bz) \
        int buf = i & 1; \
        if ((tid & 63) == 63){ \
            sA[buf][tid >> 6] = make_float4(bx, by, bz, __uint_as_float((unsigned)(bp >> 32))); \
            sB[buf][tid >> 6] = (unsigned)bp; \
        } \
        __syncthreads(); \
        float4 w0 = sA[buf][0]; \
        unsigned long long pp = ((unsigned long long)__float_as_uint(w0.w) << 32) | sB[buf][0]; \
        lx = w0.x; ly = w0.y; lz = w0.z; \
        _Pragma("unroll") \
        for (int k = 1; k < NW; ++k){ \
            float4 wk = sA[buf][k]; \
            unsigned long long pk = ((unsigned long long)__float_as_uint(wk.w) << 32) | sB[buf][k]; \
            bool c = pk > pp; \
            pp = c ? pk : pp; lx = c ? wk.x : lx; ly = c ? wk.y : ly; lz = c ? wk.z : lz; \
        } \
        if (tid == 0) sidx[(size_t)b * NPOINT + i] = (int)~(unsigned)pp; \
    }

// single-wave (64 threads): no barrier, readlane broadcast from lane 63
#define FPS_BODY_SW(RPT, N_P, NP_P) \
    constexpr int N = N_P, NPOINT = NP_P, T = 64; \
    const int b = blockIdx.x; \
    const float* X = xyz + (size_t)b * 3 * N; \
    int tid = threadIdx.x; \
    RPT(FPS_DECL) RPT(FPS_LOAD) RPT(FPS_PIN) \
    if (tid == 0) sidx[(size_t)b * NPOINT] = 0; \
    float lx = X[0], ly = X[N], lz = X[2 * N]; \
    for (int i = 1; i < NPOINT; ++i){ \
        unsigned long long bp = 0; float bx = 0.f, by = 0.f, bz = 0.f; \
        RPT(FPS_UPD) \
        DPP_REDUCE(bp, bx, by, bz) \
        lx = __int_as_float(__builtin_amdgcn_readlane(__float_as_int(bx), 63)); \
        ly = __int_as_float(__builtin_amdgcn_readlane(__float_as_int(by), 63)); \
        lz = __int_as_float(__builtin_amdgcn_readlane(__float_as_int(bz), 63)); \
        unsigned wl = (unsigned)__builtin_amdgcn_readlane((int)(unsigned)bp, 63); \
        if (tid == 0) sidx[(size_t)b * NPOINT + i] = (int)~wl; \
    }

__global__ void __launch_bounds__(512, 1)
k_fps16(const float* __restrict__ xyz, int* __restrict__ sidx){
    FPS_BODY_MW(RPT8, 4096, 1024, 512, 8)
}
__global__ void __launch_bounds__(64, 1)
k_fps4(const float* __restrict__ xyz, int* __restrict__ sidx){
    FPS_BODY_SW(RPT16, 1024, 256)
}
__global__ void __launch_bounds__(64, 1)
k_fps1(const float* __restrict__ xyz, int* __restrict__ sidx){
    FPS_BODY_SW(RPT4, 256, 64)
}

// ---------------- gather sampled xyz ----------------
__global__ void k_gather_xyz(const float* __restrict__ xyz, const int* __restrict__ sidx,
                             float* __restrict__ out, int n, int np){
    int t = blockIdx.x * blockDim.x + threadIdx.x;
    if (t >= 8 * 3 * np) return;
    int m = t % np;
    int c = (t / np) % 3;
    int b = t / (3 * np);
    out[((size_t)b * 3 + c) * np + m] = xyz[((size_t)b * 3 + c) * n + sidx[(size_t)b * np + m]];
}

// ---------------- max-pool over k grouped neighbors ----------------
__global__ void k_pool_max(const float* __restrict__ src, const int* __restrict__ idx,
                           float* __restrict__ out, int np, int nsrc){
    int m = blockIdx.x * blockDim.x + threadIdx.x;
    if (m >= np) return;
    int d = blockIdx.y, b = blockIdx.z;
    const float* row = src + ((size_t)b * 64 + d) * nsrc;
    const int* id = idx + ((size_t)b * np + m) * 8;
    float v = -FLT_MAX;
    #pragma unroll
    for (int k = 0; k < 8; ++k) v = fmaxf(v, row[id[k]]);
    out[((size_t)b * 64 + d) * np + m] = v;
}

// ---------------- neighbor sum of leaky(points), 8 d-rows per thread ----------------
// r7: old version re-loaded the same 8 indices for each of 64 d-rows (64x
// redundant idx traffic + addr calc). Batch 8 consecutive d per thread; sum
// order per output unchanged (ascending k) -> bit-identical.
__global__ void k_gather_sum(const float* __restrict__ src, const int* __restrict__ idx,
                             float* __restrict__ out, int n){
    int m = blockIdx.x * blockDim.x + threadIdx.x;
    if (m >= n) return;
    int d0 = blockIdx.y * 8, b = blockIdx.z;
    const int* id = idx + ((size_t)b * n + m) * 8;
    int i0 = id[0], i1 = id[1], i2 = id[2], i3 = id[3];
    int i4 = id[4], i5 = id[5], i6 = id[6], i7 = id[7];
    const float* base = src + (size_t)b * 64 * n;
    float* ob = out + (size_t)b * 64 * n;
    #pragma unroll
    for (int dd = 0; dd < 8; ++dd){
        const float* row = base + (size_t)(d0 + dd) * n;
        float v = 0.f;
        v += leaky(row[i0]); v += leaky(row[i1]); v += leaky(row[i2]); v += leaky(row[i3]);
        v += leaky(row[i4]); v += leaky(row[i5]); v += leaky(row[i6]); v += leaky(row[i7]);
        ob[(size_t)(d0 + dd) * n + m] = v;
    }
}

// ---------------- dual GEMM + epilogue: out = (wc@leaky(P) + wg@S)/9 + P ----------------
// 4 output-groups of 16 named accumulators; block = 64 cols x 4 groups so each
// wave is one group and weight reads stay wave-uniform s_loads.
#define RC_DECL(i) float a##i = 0.f;
#define RC_FMA(i)  a##i = fmaf(wc[i], h, fmaf(wg[i], sv, a##i));
#define RC_STORE(i) O[(size_t)(i) * n] = a##i * inv + Pr[(size_t)(i) * n];

__global__ void __launch_bounds__(256, 1)
k_res_conv(const float* __restrict__ pts, const float* __restrict__ s,
           const float* __restrict__ wcT, const float* __restrict__ wgT,
           float* __restrict__ out, int n){
    int j = blockIdx.x * 64 + threadIdx.x;   // column
    int g = threadIdx.y;                     // output group (wave-uniform)
    if (j >= n) return;
    int b = blockIdx.y;
    const float* P = pts + (size_t)b * 64 * n + j;
    const float* S = s   + (size_t)b * 64 * n + j;
    RPT16(RC_DECL)
    for (int d = 0; d < 64; ++d){
        float h  = leaky(P[(size_t)d * n]);
        float sv = S[(size_t)d * n];
        const float* wc = wcT + d * 64 + g * 16;  // wave-uniform -> s_load
        const float* wg = wgT + d * 64 + g * 16;
        RPT16(RC_FMA)
    }
    const float inv = 1.0f / 9.0f;
    float* O = out + ((size_t)b * 64 + g * 16) * n + j;
    const float* Pr = P + (size_t)(g * 16) * n;
    RPT16(RC_STORE)
}

// ---------------- last layer: leaky -> 1x1 conv to 1 channel ----------------
__global__ void k_final(const float* __restrict__ pts, const float* __restrict__ wl,
                        float* __restrict__ out){
    int t = blockIdx.x * blockDim.x + threadIdx.x;
    if (t >= 512) return;
    int b = t >> 6, m = t & 63;
    const float* P = pts + (size_t)b * 64 * 64;
    float acc = 0.f;
    for (int d = 0; d < 64; ++d) acc += wl[d] * leaky(P[d * 64 + m]);
    out[t] = acc;
}

extern "C" void kernel_launch(void* const* d_in, const int* in_sizes, int n_in,
                              void* d_out, int out_size, void* d_ws, size_t ws_size,
                              hipStream_t stream){
    const float* xyz_in  = (const float*)d_in[0];
    const float* w0      = (const float*)d_in[1];
    const float* fn_wc   = (const float*)d_in[2];
    const float* fn_wg   = (const float*)d_in[3];
    const float* res_wc  = (const float*)d_in[4];
    const float* res_wg  = (const float*)d_in[5];
    const float* w_last  = (const float*)d_in[6];
    float* out = (float*)d_out;

    char* ws = (char*)d_ws;
    size_t off = 0;
    auto alloc = [&](size_t bytes) -> char* {
        char* p = ws + off;
        off = (off + bytes + 255) & ~(size_t)255;
        return p;
    };
    float* wT_fnc = (float*)alloc(2UL  * 4096 * 4);
    float* wT_fng = (float*)alloc(2UL  * 4096 * 4);
    float* wT_rc  = (float*)alloc(12UL * 4096 * 4);
    float* wT_rg  = (float*)alloc(12UL * 4096 * 4);
    float* pts_a  = (float*)alloc(8UL * 64 * 4096 * 4);
    float* pts_b  = (float*)alloc(8UL * 64 * 4096 * 4);
    float* s_buf  = (float*)alloc(8UL * 64 * 4096 * 4);
    int*   idx_b  = (int*)  alloc(8UL * 4096 * 8 * 4);
    float* xyz1   = (float*)alloc(8UL * 3 * 1024 * 4);
    float* xyz2   = (float*)alloc(8UL * 3 * 1024 * 4);
    int*   sidx   = (int*)  alloc(8UL * 1024 * 4);

    // transpose all weight matrices to [d][o]
    k_transpose<<<2,  256, 0, stream>>>(fn_wc,  wT_fnc);
    k_transpose<<<2,  256, 0, stream>>>(fn_wg,  wT_fng);
    k_transpose<<<12, 256, 0, stream>>>(res_wc, wT_rc);
    k_transpose<<<12, 256, 0, stream>>>(res_wg, wT_rg);

    int n = 4096;
    k_conv0<<<(8 * 64 * n) / 256, 256, 0, stream>>>(xyz_in, w0, pts_a, n);

    const float* cxyz = xyz_in;
    {
        dim3 kb((n + BKNN - 1) / BKNN, 8);
        k_knn<<<kb, BKNN, 0, stream>>>(cxyz, cxyz, n, n, idx_b);
    }
    float* pc = pts_a;
    float* pn = pts_b;
    dim3 rcb(64, 4);
    for (int j = 0; j < 2; ++j){
        dim3 g((n + 255) / 256, 8, 8);
        k_gather_sum<<<g, 256, 0, stream>>>(pc, idx_b, s_buf, n);
        dim3 g2((n + 63) / 64, 8);
        k_res_conv<<<g2, rcb, 0, stream>>>(pc, s_buf, wT_fnc + j * 4096, wT_fng + j * 4096, pn, n);
        float* t = pc; pc = pn; pn = t;
    }

    float* xyzbufs[2] = {xyz1, xyz2};
    for (int l = 0; l < 3; ++l){
        int np = n / 4;
        if (n == 4096)      k_fps16<<<8, 512, 0, stream>>>(cxyz, sidx);
        else if (n == 1024) k_fps4<<<8, 64, 0, stream>>>(cxyz, sidx);
        else                k_fps1<<<8, 64, 0, stream>>>(cxyz, sidx);

        float* nxyz = xyzbufs[l & 1];
        int tot = 8 * 3 * np;
        k_gather_xyz<<<(tot + 255) / 256, 256, 0, stream>>>(cxyz, sidx, nxyz, n, np);

        dim3 kg((np + BKNN - 1) / BKNN, 8);
        k_knn<<<kg, BKNN, 0, stream>>>(nxyz, cxyz, np, n, idx_b);

        dim3 pm((np + 255) / 256, 64, 8);
        k_pool_max<<<pm, 256, 0, stream>>>(pc, idx_b, pn, np, n);
        float* t = pc; pc = pn; pn = t;

        cxyz = nxyz; n = np;

        dim3 ks((n + BKNN - 1) / BKNN, 8);
        k_knn<<<ks, BKNN, 0, stream>>>(cxyz, cxyz, n, n, idx_b);

        for (int i = 0; i < 4; ++i){
            dim3 g((n + 255) / 256, 8, 8);
            k_gather_sum<<<g, 256, 0, stream>>>(pc, idx_b, s_buf, n);
            dim3 g2((n + 63) / 64, 8);
            k_res_conv<<<g2, rcb, 0, stream>>>(pc, s_buf, wT_rc + (l * 4 + i) * 4096,
                                               wT_rg + (l * 4 + i) * 4096, pn, n);
            t = pc; pc = pn; pn = t;
        }
    }

    k_final<<<2, 256, 0, stream>>>(pc, w_last, out);
}

// Round 9
// 2879.820 us; speedup vs baseline: 1.0091x; 1.0091x over previous
//
#include <hip/hip_runtime.h>
#include <hip/hip_bf16.h>
#include <float.h>

#define NEG_SLOPE 0.01f

__device__ __forceinline__ float leaky(float x){ return x >= 0.0f ? x : NEG_SLOPE * x; }

// ---------------- transpose a batch of 64x64 matrices: [o][d] -> [d][o] ----------------
__global__ void k_transpose(const float* __restrict__ src, float* __restrict__ dst){
    int m = blockIdx.x;
    const float* s = src + (size_t)m * 4096;
    float* d = dst + (size_t)m * 4096;
    for (int t = threadIdx.x; t < 4096; t += blockDim.x){
        int o = t >> 6, dd = t & 63;
        d[dd * 64 + o] = s[t];
    }
}

// ---------------- first conv: 3 -> 64 ----------------
__global__ void k_conv0(const float* __restrict__ xyz, const float* __restrict__ w0,
                        float* __restrict__ out, int n){
    int t = blockIdx.x * blockDim.x + threadIdx.x;
    int nn = t % n;
    int rest = t / n;
    int o = rest & 63;
    int b = rest >> 6;
    const float* X = xyz + (size_t)b * 3 * n;
    float x = X[nn], y = X[n + nn], z = X[2 * n + nn];
    out[((size_t)b * 64 + o) * n + nn] = w0[o*3] * x + w0[o*3+1] * y + w0[o*3+2] * z;
}

// ---------------- kNN: for each query, indices of 8 nearest refs ----------------
#define KNN_CHUNK 1024
#define BKNN 64

#define KNN_INS(bdX, biX) { bool c = cd < bdX; float tf = bdX; int ti = biX; \
    bdX = c ? cd : bdX; biX = c ? ci : biX; cd = c ? tf : cd; ci = c ? ti : ci; }

__global__ void __launch_bounds__(BKNN, 1)
k_knn(const float* __restrict__ q, const float* __restrict__ ref,
      int M, int Nr, int* __restrict__ idx_out){
    __shared__ float4 sref[KNN_CHUNK];
    int b = blockIdx.y;
    int m = blockIdx.x * BKNN + threadIdx.x;
    const float* Q = q + (size_t)b * 3 * M;
    const float* R = ref + (size_t)b * 3 * Nr;
    bool valid = (m < M);
    float qx = 0.f, qy = 0.f, qz = 0.f, qq = 0.f;
    if (valid){
        qx = Q[m]; qy = Q[M + m]; qz = Q[2 * M + m];
        qq = qx*qx + qy*qy + qz*qz;
    }
    float bd0 = FLT_MAX, bd1 = FLT_MAX, bd2 = FLT_MAX, bd3 = FLT_MAX;
    float bd4 = FLT_MAX, bd5 = FLT_MAX, bd6 = FLT_MAX, bd7 = FLT_MAX;
    int bi0 = 0, bi1 = 0, bi2 = 0, bi3 = 0, bi4 = 0, bi5 = 0, bi6 = 0, bi7 = 0;

    for (int base = 0; base < Nr; base += KNN_CHUNK){
        int jmax = min(KNN_CHUNK, Nr - base);
        for (int j = threadIdx.x; j < jmax; j += BKNN){
            float rx = R[base + j], ry = R[Nr + base + j], rz = R[2 * Nr + base + j];
            sref[j] = make_float4(rx, ry, rz, rx*rx + ry*ry + rz*rz);
        }
        __syncthreads();
        for (int j = 0; j < jmax; ++j){
            float4 r = sref[j];
            float dot = qx * r.x + qy * r.y + qz * r.z;
            float d = qq + r.w - 2.0f * dot;
            if (d < bd7){
                // ascending-index scan + strict '<' => lowest index wins ties (matches lax.top_k)
                float cd = d; int ci = base + j;
                KNN_INS(bd0, bi0); KNN_INS(bd1, bi1); KNN_INS(bd2, bi2); KNN_INS(bd3, bi3);
                KNN_INS(bd4, bi4); KNN_INS(bd5, bi5); KNN_INS(bd6, bi6); KNN_INS(bd7, bi7);
            }
        }
        __syncthreads();
    }
    if (valid){
        int* o = idx_out + ((size_t)b * M + m) * 8;
        o[0] = bi0; o[1] = bi1; o[2] = bi2; o[3] = bi3;
        o[4] = bi4; o[5] = bi5; o[6] = bi6; o[7] = bi7;
    }
}

// ---------------- farthest point sampling ----------------
// DPP reduction on the VALU; candidate packed as (float_bits(dist)<<32)|~idx
// for exact single-cmp tie-breaks; winner coords ride the DPP selects.
// r8 post-mortem: T=512 regressed (823 vs 765) -- per-SIMD update issue is
// constant but DPP+combine cost scales with waves/SIMD. T=256/P=16 is optimal.

template<int CTRL>
__device__ __forceinline__ void dpp_step(unsigned long long &bp, float &x, float &y, float &z){
    unsigned h = (unsigned)(bp >> 32), l = (unsigned)bp;
    unsigned th = (unsigned)__builtin_amdgcn_update_dpp(0, (int)h, CTRL, 0xF, 0xF, true);
    unsigned tl = (unsigned)__builtin_amdgcn_update_dpp(0, (int)l, CTRL, 0xF, 0xF, true);
    float tx = __int_as_float(__builtin_amdgcn_update_dpp(0, __float_as_int(x), CTRL, 0xF, 0xF, true));
    float ty = __int_as_float(__builtin_amdgcn_update_dpp(0, __float_as_int(y), CTRL, 0xF, 0xF, true));
    float tz = __int_as_float(__builtin_amdgcn_update_dpp(0, __float_as_int(z), CTRL, 0xF, 0xF, true));
    unsigned long long tp = ((unsigned long long)th << 32) | tl;
    bool c = tp > bp;
    bp = c ? tp : bp; x = c ? tx : x; y = c ? ty : y; z = c ? tz : z;
}
// after these 6 steps lane 63 holds the wave's max (with coords)
#define DPP_REDUCE(bp, bx, by, bz) \
    dpp_step<0x111>(bp, bx, by, bz); \
    dpp_step<0x112>(bp, bx, by, bz); \
    dpp_step<0x114>(bp, bx, by, bz); \
    dpp_step<0x118>(bp, bx, by, bz); \
    dpp_step<0x142>(bp, bx, by, bz); \
    dpp_step<0x143>(bp, bx, by, bz);

#define FPS_DECL(i) float px##i, py##i, pz##i, ds##i; unsigned nti##i;
#define FPS_LOAD(i) { int gi = tid + (i) * T; px##i = X[gi]; py##i = X[N + gi]; \
                      pz##i = X[2 * N + gi]; ds##i = 1e10f; nti##i = ~(unsigned)gi; }
#define FPS_PIN(i) asm volatile("" : "+v"(px##i), "+v"(py##i), "+v"(pz##i));
// dist >= 0 always => float bit pattern order == float order; ~gi larger => gi smaller,
// so u64 max reproduces (dist >, tie: idx <) exactly.
#define FPS_UPD(i) { float dx = px##i - lx, dy = py##i - ly, dz = pz##i - lz; \
    float d = dx*dx + dy*dy + dz*dz; \
    float nd = fminf(ds##i, d); ds##i = nd; \
    unsigned long long cp = ((unsigned long long)__float_as_uint(nd) << 32) | nti##i; \
    bool c = cp > bp; \
    bp = c ? cp : bp; bx = c ? px##i : bx; by = c ? py##i : by; bz = c ? pz##i : bz; }

#define RPT16(M) M(0) M(1) M(2) M(3) M(4) M(5) M(6) M(7) \
                 M(8) M(9) M(10) M(11) M(12) M(13) M(14) M(15)
#define RPT4(M) M(0) M(1) M(2) M(3)

// multi-wave: one barrier/iter, per-wave winners (with coords) combined via LDS
#define FPS_BODY_MW(RPT, N_P, NP_P, T_P, NW) \
    constexpr int N = N_P, NPOINT = NP_P, T = T_P; \
    const int b = blockIdx.x; \
    const float* X = xyz + (size_t)b * 3 * N; \
    int tid = threadIdx.x; \
    RPT(FPS_DECL) RPT(FPS_LOAD) RPT(FPS_PIN) \
    __shared__ float4 sA[2][NW]; \
    __shared__ unsigned sB[2][NW]; \
    if (tid == 0) sidx[(size_t)b * NPOINT] = 0; \
    float lx = X[0], ly = X[N], lz = X[2 * N]; \
    for (int i = 1; i < NPOINT; ++i){ \
        unsigned long long bp = 0; float bx = 0.f, by = 0.f, bz = 0.f; \
        RPT(FPS_UPD) \
        DPP_REDUCE(bp, bx, by, bz) \
        int buf = i & 1; \
        if ((tid & 63) == 63){ \
            sA[buf][tid >> 6] = make_float4(bx, by, bz, __uint_as_float((unsigned)(bp >> 32))); \
            sB[buf][tid >> 6] = (unsigned)bp; \
        } \
        __syncthreads(); \
        float4 w0 = sA[buf][0]; \
        unsigned long long pp = ((unsigned long long)__float_as_uint(w0.w) << 32) | sB[buf][0]; \
        lx = w0.x; ly = w0.y; lz = w0.z; \
        _Pragma("unroll") \
        for (int k = 1; k < NW; ++k){ \
            float4 wk = sA[buf][k]; \
            unsigned long long pk = ((unsigned long long)__float_as_uint(wk.w) << 32) | sB[buf][k]; \
            bool c = pk > pp; \
            pp = c ? pk : pp; lx = c ? wk.x : lx; ly = c ? wk.y : ly; lz = c ? wk.z : lz; \
        } \
        if (tid == 0) sidx[(size_t)b * NPOINT + i] = (int)~(unsigned)pp; \
    }

// single-wave (64 threads): no barrier, readlane broadcast from lane 63
#define FPS_BODY_SW(RPT, N_P, NP_P) \
    constexpr int N = N_P, NPOINT = NP_P, T = 64; \
    const int b = blockIdx.x; \
    const float* X = xyz + (size_t)b * 3 * N; \
    int tid = threadIdx.x; \
    RPT(FPS_DECL) RPT(FPS_LOAD) RPT(FPS_PIN) \
    if (tid == 0) sidx[(size_t)b * NPOINT] = 0; \
    float lx = X[0], ly = X[N], lz = X[2 * N]; \
    for (int i = 1; i < NPOINT; ++i){ \
        unsigned long long bp = 0; float bx = 0.f, by = 0.f, bz = 0.f; \
        RPT(FPS_UPD) \
        DPP_REDUCE(bp, bx, by, bz) \
        lx = __int_as_float(__builtin_amdgcn_readlane(__float_as_int(bx), 63)); \
        ly = __int_as_float(__builtin_amdgcn_readlane(__float_as_int(by), 63)); \
        lz = __int_as_float(__builtin_amdgcn_readlane(__float_as_int(bz), 63)); \
        unsigned wl = (unsigned)__builtin_amdgcn_readlane((int)(unsigned)bp, 63); \
        if (tid == 0) sidx[(size_t)b * NPOINT + i] = (int)~wl; \
    }

__global__ void __launch_bounds__(256, 1)
k_fps16(const float* __restrict__ xyz, int* __restrict__ sidx){
    FPS_BODY_MW(RPT16, 4096, 1024, 256, 4)
}
__global__ void __launch_bounds__(64, 1)
k_fps4(const float* __restrict__ xyz, int* __restrict__ sidx){
    FPS_BODY_SW(RPT16, 1024, 256)
}
__global__ void __launch_bounds__(64, 1)
k_fps1(const float* __restrict__ xyz, int* __restrict__ sidx){
    FPS_BODY_SW(RPT4, 256, 64)
}

// ---------------- gather sampled xyz ----------------
__global__ void k_gather_xyz(const float* __restrict__ xyz, const int* __restrict__ sidx,
                             float* __restrict__ out, int n, int np){
    int t = blockIdx.x * blockDim.x + threadIdx.x;
    if (t >= 8 * 3 * np) return;
    int m = t % np;
    int c = (t / np) % 3;
    int b = t / (3 * np);
    out[((size_t)b * 3 + c) * np + m] = xyz[((size_t)b * 3 + c) * n + sidx[(size_t)b * np + m]];
}

// ---------------- dim-major [64][n] -> point-major [n][64] tiled transpose ----------------
// r8: the random gathers in gather_sum/pool_max hit ~55 cache lines per wave
// gather AND re-gather the same indices for all 64 d. Point-major layout makes
// one neighbor's 64-d vector 256B contiguous -> wave-coalesced loads.
__global__ void __launch_bounds__(256, 1)
k_to_pm(const float* __restrict__ dm, float* __restrict__ pm, int n){
    __shared__ float tile[64][65];
    int b = blockIdx.y;
    int j0 = blockIdx.x * 64;
    int lane = threadIdx.x & 63;
    int w = threadIdx.x >> 6;
    const float* S = dm + (size_t)b * 64 * n + j0;
    #pragma unroll
    for (int c = 0; c < 16; ++c){
        int d = w * 16 + c;
        tile[d][lane] = S[(size_t)d * n + lane];      // coalesced read
    }
    __syncthreads();
    float* O = pm + ((size_t)b * n + j0) * 64;
    #pragma unroll
    for (int c = 0; c < 16; ++c){
        int jl = w * 16 + c;
        O[(size_t)jl * 64 + lane] = tile[lane][jl];   // coalesced write, pad kills conflicts
    }
}

// ---------------- neighbor sum of leaky, point-major input (wave per column) ----------------
// Wave w handles 16 columns; for each column: 8 COALESCED 256B loads (lane = d),
// register accumulate (ascending k -> bit-identical), LDS-transposed dim-major store.
__global__ void __launch_bounds__(256, 1)
k_gather_sum_pm(const float* __restrict__ pm, const int* __restrict__ idx,
                float* __restrict__ out, int n){
    __shared__ float tile[64][65];
    int b = blockIdx.y;
    int j0 = blockIdx.x * 64;
    int lane = threadIdx.x & 63;
    int w = threadIdx.x >> 6;
    const float* PM = pm + (size_t)b * n * 64;
    const int* ID = idx + ((size_t)b * n + j0) * 8;
    for (int c = 0; c < 16; ++c){
        int jl = w * 16 + c;
        const int* id = ID + jl * 8;
        float v = 0.f;
        #pragma unroll
        for (int k = 0; k < 8; ++k)
            v += leaky(PM[(size_t)id[k] * 64 + lane]);
        tile[jl][lane] = v;
    }
    __syncthreads();
    float* O = out + (size_t)b * 64 * n + j0;
    for (int c = 0; c < 16; ++c){
        int d = w * 16 + c;
        O[(size_t)d * n + lane] = tile[lane][d];
    }
}

// ---------------- max-pool over k neighbors, point-major input ----------------
__global__ void __launch_bounds__(256, 1)
k_pool_max_pm(const float* __restrict__ pm, const int* __restrict__ idx,
              float* __restrict__ out, int np, int nsrc){
    __shared__ float tile[64][65];
    int b = blockIdx.y;
    int m0 = blockIdx.x * 64;
    int lane = threadIdx.x & 63;
    int w = threadIdx.x >> 6;
    const float* PM = pm + (size_t)b * nsrc * 64;
    const int* ID = idx + ((size_t)b * np + m0) * 8;
    for (int c = 0; c < 16; ++c){
        int ml = w * 16 + c;
        const int* id = ID + ml * 8;
        float v = -FLT_MAX;
        #pragma unroll
        for (int k = 0; k < 8; ++k)
            v = fmaxf(v, PM[(size_t)id[k] * 64 + lane]);
        tile[ml][lane] = v;
    }
    __syncthreads();
    float* O = out + (size_t)b * 64 * np + m0;
    for (int c = 0; c < 16; ++c){
        int d = w * 16 + c;
        O[(size_t)d * np + lane] = tile[lane][d];
    }
}

// ---------------- old scattered-gather kernels (small n only) ----------------
__global__ void k_pool_max(const float* __restrict__ src, const int* __restrict__ idx,
                           float* __restrict__ out, int np, int nsrc){
    int m = blockIdx.x * blockDim.x + threadIdx.x;
    if (m >= np) return;
    int d = blockIdx.y, b = blockIdx.z;
    const float* row = src + ((size_t)b * 64 + d) * nsrc;
    const int* id = idx + ((size_t)b * np + m) * 8;
    float v = -FLT_MAX;
    #pragma unroll
    for (int k = 0; k < 8; ++k) v = fmaxf(v, row[id[k]]);
    out[((size_t)b * 64 + d) * np + m] = v;
}

__global__ void k_gather_sum(const float* __restrict__ src, const int* __restrict__ idx,
                             float* __restrict__ out, int n){
    int m = blockIdx.x * blockDim.x + threadIdx.x;
    if (m >= n) return;
    int d0 = blockIdx.y * 8, b = blockIdx.z;
    const int* id = idx + ((size_t)b * n + m) * 8;
    int i0 = id[0], i1 = id[1], i2 = id[2], i3 = id[3];
    int i4 = id[4], i5 = id[5], i6 = id[6], i7 = id[7];
    const float* base = src + (size_t)b * 64 * n;
    float* ob = out + (size_t)b * 64 * n;
    #pragma unroll
    for (int dd = 0; dd < 8; ++dd){
        const float* row = base + (size_t)(d0 + dd) * n;
        float v = 0.f;
        v += leaky(row[i0]); v += leaky(row[i1]); v += leaky(row[i2]); v += leaky(row[i3]);
        v += leaky(row[i4]); v += leaky(row[i5]); v += leaky(row[i6]); v += leaky(row[i7]);
        ob[(size_t)(d0 + dd) * n + m] = v;
    }
}

// ---------------- dual GEMM + epilogue: out = (wc@leaky(P) + wg@S)/9 + P ----------------
#define RC_DECL(i) float a##i = 0.f;
#define RC_FMA(i)  a##i = fmaf(wc[i], h, fmaf(wg[i], sv, a##i));
#define RC_STORE(i) O[(size_t)(i) * n] = a##i * inv + Pr[(size_t)(i) * n];

__global__ void __launch_bounds__(256, 1)
k_res_conv(const float* __restrict__ pts, const float* __restrict__ s,
           const float* __restrict__ wcT, const float* __restrict__ wgT,
           float* __restrict__ out, int n){
    int j = blockIdx.x * 64 + threadIdx.x;   // column
    int g = threadIdx.y;                     // output group (wave-uniform)
    if (j >= n) return;
    int b = blockIdx.y;
    const float* P = pts + (size_t)b * 64 * n + j;
    const float* S = s   + (size_t)b * 64 * n + j;
    RPT16(RC_DECL)
    for (int d = 0; d < 64; ++d){
        float h  = leaky(P[(size_t)d * n]);
        float sv = S[(size_t)d * n];
        const float* wc = wcT + d * 64 + g * 16;  // wave-uniform -> s_load
        const float* wg = wgT + d * 64 + g * 16;
        RPT16(RC_FMA)
    }
    const float inv = 1.0f / 9.0f;
    float* O = out + ((size_t)b * 64 + g * 16) * n + j;
    const float* Pr = P + (size_t)(g * 16) * n;
    RPT16(RC_STORE)
}

// ---------------- last layer: leaky -> 1x1 conv to 1 channel ----------------
__global__ void k_final(const float* __restrict__ pts, const float* __restrict__ wl,
                        float* __restrict__ out){
    int t = blockIdx.x * blockDim.x + threadIdx.x;
    if (t >= 512) return;
    int b = t >> 6, m = t & 63;
    const float* P = pts + (size_t)b * 64 * 64;
    float acc = 0.f;
    for (int d = 0; d < 64; ++d) acc += wl[d] * leaky(P[d * 64 + m]);
    out[t] = acc;
}

extern "C" void kernel_launch(void* const* d_in, const int* in_sizes, int n_in,
                              void* d_out, int out_size, void* d_ws, size_t ws_size,
                              hipStream_t stream){
    const float* xyz_in  = (const float*)d_in[0];
    const float* w0      = (const float*)d_in[1];
    const float* fn_wc   = (const float*)d_in[2];
    const float* fn_wg   = (const float*)d_in[3];
    const float* res_wc  = (const float*)d_in[4];
    const float* res_wg  = (const float*)d_in[5];
    const float* w_last  = (const float*)d_in[6];
    float* out = (float*)d_out;

    char* ws = (char*)d_ws;
    size_t off = 0;
    auto alloc = [&](size_t bytes) -> char* {
        char* p = ws + off;
        off = (off + bytes + 255) & ~(size_t)255;
        return p;
    };
    float* wT_fnc = (float*)alloc(2UL  * 4096 * 4);
    float* wT_fng = (float*)alloc(2UL  * 4096 * 4);
    float* wT_rc  = (float*)alloc(12UL * 4096 * 4);
    float* wT_rg  = (float*)alloc(12UL * 4096 * 4);
    float* pts_a  = (float*)alloc(8UL * 64 * 4096 * 4);
    float* pts_b  = (float*)alloc(8UL * 64 * 4096 * 4);
    float* s_buf  = (float*)alloc(8UL * 64 * 4096 * 4);
    float* pm_buf = (float*)alloc(8UL * 64 * 4096 * 4);
    int*   idx_b  = (int*)  alloc(8UL * 4096 * 8 * 4);
    float* xyz1   = (float*)alloc(8UL * 3 * 1024 * 4);
    float* xyz2   = (float*)alloc(8UL * 3 * 1024 * 4);
    int*   sidx   = (int*)  alloc(8UL * 1024 * 4);

    // transpose all weight matrices to [d][o]
    k_transpose<<<2,  256, 0, stream>>>(fn_wc,  wT_fnc);
    k_transpose<<<2,  256, 0, stream>>>(fn_wg,  wT_fng);
    k_transpose<<<12, 256, 0, stream>>>(res_wc, wT_rc);
    k_transpose<<<12, 256, 0, stream>>>(res_wg, wT_rg);

    int n = 4096;
    k_conv0<<<(8 * 64 * n) / 256, 256, 0, stream>>>(xyz_in, w0, pts_a, n);

    const float* cxyz = xyz_in;
    {
        dim3 kb((n + BKNN - 1) / BKNN, 8);
        k_knn<<<kb, BKNN, 0, stream>>>(cxyz, cxyz, n, n, idx_b);
    }
    float* pc = pts_a;
    float* pn = pts_b;
    dim3 rcb(64, 4);
    for (int j = 0; j < 2; ++j){
        dim3 tp(n / 64, 8);
        k_to_pm<<<tp, 256, 0, stream>>>(pc, pm_buf, n);
        k_gather_sum_pm<<<tp, 256, 0, stream>>>(pm_buf, idx_b, s_buf, n);
        dim3 g2((n + 63) / 64, 8);
        k_res_conv<<<g2, rcb, 0, stream>>>(pc, s_buf, wT_fnc + j * 4096, wT_fng + j * 4096, pn, n);
        float* t = pc; pc = pn; pn = t;
    }

    float* xyzbufs[2] = {xyz1, xyz2};
    for (int l = 0; l < 3; ++l){
        int np = n / 4;
        if (n == 4096)      k_fps16<<<8, 256, 0, stream>>>(cxyz, sidx);
        else if (n == 1024) k_fps4<<<8, 64, 0, stream>>>(cxyz, sidx);
        else                k_fps1<<<8, 64, 0, stream>>>(cxyz, sidx);

        float* nxyz = xyzbufs[l & 1];
        int tot = 8 * 3 * np;
        k_gather_xyz<<<(tot + 255) / 256, 256, 0, stream>>>(cxyz, sidx, nxyz, n, np);

        dim3 kg((np + BKNN - 1) / BKNN, 8);
        k_knn<<<kg, BKNN, 0, stream>>>(nxyz, cxyz, np, n, idx_b);

        if (n >= 1024){
            dim3 tp(n / 64, 8);
            k_to_pm<<<tp, 256, 0, stream>>>(pc, pm_buf, n);
            dim3 pp(np / 64, 8);
            k_pool_max_pm<<<pp, 256, 0, stream>>>(pm_buf, idx_b, pn, np, n);
        } else {
            dim3 pm((np + 255) / 256, 64, 8);
            k_pool_max<<<pm, 256, 0, stream>>>(pc, idx_b, pn, np, n);
        }
        float* t = pc; pc = pn; pn = t;

        cxyz = nxyz; n = np;

        dim3 ks((n + BKNN - 1) / BKNN, 8);
        k_knn<<<ks, BKNN, 0, stream>>>(cxyz, cxyz, n, n, idx_b);

        for (int i = 0; i < 4; ++i){
            if (n >= 1024){
                dim3 tp(n / 64, 8);
                k_to_pm<<<tp, 256, 0, stream>>>(pc, pm_buf, n);
                k_gather_sum_pm<<<tp, 256, 0, stream>>>(pm_buf, idx_b, s_buf, n);
            } else {
                dim3 g((n + 255) / 256, 8, 8);
                k_gather_sum<<<g, 256, 0, stream>>>(pc, idx_b, s_buf, n);
            }
            dim3 g2((n + 63) / 64, 8);
            k_res_conv<<<g2, rcb, 0, stream>>>(pc, s_buf, wT_rc + (l * 4 + i) * 4096,
                                               wT_rg + (l * 4 + i) * 4096, pn, n);
            t = pc; pc = pn; pn = t;
        }
    }

    k_final<<<2, 256, 0, stream>>>(pc, w_last, out);
}

// Round 10
// 2606.997 us; speedup vs baseline: 1.1147x; 1.1047x over previous
//
#include <hip/hip_runtime.h>
#include <hip/hip_bf16.h>
#include <float.h>

#define NEG_SLOPE 0.01f

typedef float v2f __attribute__((ext_vector_type(2)));

__device__ __forceinline__ float leaky(float x){ return x >= 0.0f ? x : NEG_SLOPE * x; }

#if !__has_builtin(__builtin_elementwise_fma)
#error "need __builtin_elementwise_fma"
#endif

// ---------------- transpose a batch of 64x64 matrices: [o][d] -> [d][o] ----------------
__global__ void k_transpose(const float* __restrict__ src, float* __restrict__ dst){
    int m = blockIdx.x;
    const float* s = src + (size_t)m * 4096;
    float* d = dst + (size_t)m * 4096;
    for (int t = threadIdx.x; t < 4096; t += blockDim.x){
        int o = t >> 6, dd = t & 63;
        d[dd * 64 + o] = s[t];
    }
}

// ---------------- first conv: 3 -> 64 ----------------
__global__ void k_conv0(const float* __restrict__ xyz, const float* __restrict__ w0,
                        float* __restrict__ out, int n){
    int t = blockIdx.x * blockDim.x + threadIdx.x;
    int nn = t % n;
    int rest = t / n;
    int o = rest & 63;
    int b = rest >> 6;
    const float* X = xyz + (size_t)b * 3 * n;
    float x = X[nn], y = X[n + nn], z = X[2 * n + nn];
    out[((size_t)b * 64 + o) * n + nn] = w0[o*3] * x + w0[o*3+1] * y + w0[o*3+2] * z;
}

// ---------------- dim-major [64][n] -> point-major [n][64] tiled transpose ----------------
__global__ void __launch_bounds__(256, 1)
k_to_pm(const float* __restrict__ dm, float* __restrict__ pm, int n){
    __shared__ float tile[64][65];
    int b = blockIdx.y;
    int j0 = blockIdx.x * 64;
    int lane = threadIdx.x & 63;
    int w = threadIdx.x >> 6;
    const float* S = dm + (size_t)b * 64 * n + j0;
    #pragma unroll
    for (int c = 0; c < 16; ++c){
        int d = w * 16 + c;
        tile[d][lane] = S[(size_t)d * n + lane];
    }
    __syncthreads();
    float* O = pm + ((size_t)b * n + j0) * 64;
    #pragma unroll
    for (int c = 0; c < 16; ++c){
        int jl = w * 16 + c;
        O[(size_t)jl * 64 + lane] = tile[lane][jl];
    }
}

// ---------------- kNN: for each query, indices of 8 nearest refs ----------------
#define KNN_CHUNK 1024
#define BKNN 64

#define KNN_INS(bdX, biX) { bool c = cd < bdX; float tf = bdX; int ti = biX; \
    bdX = c ? cd : bdX; biX = c ? ci : biX; cd = c ? tf : cd; ci = c ? ti : ci; }

__global__ void __launch_bounds__(BKNN, 1)
k_knn(const float* __restrict__ q, const float* __restrict__ ref,
      int M, int Nr, int* __restrict__ idx_out){
    __shared__ float4 sref[KNN_CHUNK];
    int b = blockIdx.y;
    int m = blockIdx.x * BKNN + threadIdx.x;
    const float* Q = q + (size_t)b * 3 * M;
    const float* R = ref + (size_t)b * 3 * Nr;
    bool valid = (m < M);
    float qx = 0.f, qy = 0.f, qz = 0.f, qq = 0.f;
    if (valid){
        qx = Q[m]; qy = Q[M + m]; qz = Q[2 * M + m];
        qq = qx*qx + qy*qy + qz*qz;
    }
    float bd0 = FLT_MAX, bd1 = FLT_MAX, bd2 = FLT_MAX, bd3 = FLT_MAX;
    float bd4 = FLT_MAX, bd5 = FLT_MAX, bd6 = FLT_MAX, bd7 = FLT_MAX;
    int bi0 = 0, bi1 = 0, bi2 = 0, bi3 = 0, bi4 = 0, bi5 = 0, bi6 = 0, bi7 = 0;

    for (int base = 0; base < Nr; base += KNN_CHUNK){
        int jmax = min(KNN_CHUNK, Nr - base);
        for (int j = threadIdx.x; j < jmax; j += BKNN){
            float rx = R[base + j], ry = R[Nr + base + j], rz = R[2 * Nr + base + j];
            sref[j] = make_float4(rx, ry, rz, rx*rx + ry*ry + rz*rz);
        }
        __syncthreads();
        for (int j = 0; j < jmax; ++j){
            float4 r = sref[j];
            float dot = qx * r.x + qy * r.y + qz * r.z;
            float d = qq + r.w - 2.0f * dot;
            if (d < bd7){
                // ascending-index scan + strict '<' => lowest index wins ties (matches lax.top_k)
                float cd = d; int ci = base + j;
                KNN_INS(bd0, bi0); KNN_INS(bd1, bi1); KNN_INS(bd2, bi2); KNN_INS(bd3, bi3);
                KNN_INS(bd4, bi4); KNN_INS(bd5, bi5); KNN_INS(bd6, bi6); KNN_INS(bd7, bi7);
            }
        }
        __syncthreads();
    }
    if (valid){
        int* o = idx_out + ((size_t)b * M + m) * 8;
        o[0] = bi0; o[1] = bi1; o[2] = bi2; o[3] = bi3;
        o[4] = bi4; o[5] = bi5; o[6] = bi6; o[7] = bi7;
    }
}

// ---------------- farthest point sampling ----------------
// r10: (a) packed-fp32-friendly float2 distance math (pk_add/mul/fma on CDNA),
// (b) bp-only DPP argmax (key = (float_bits(dist)<<32)|~idx, exact tie-break),
// winner coords via read-only LDS xyz mirror (broadcast b128), (c) fps writes
// nxyz directly (kills gather_xyz kernel). Selection semantics unchanged.

template<int CTRL>
__device__ __forceinline__ void dpp2(unsigned long long &bp){
    unsigned h = (unsigned)(bp >> 32), l = (unsigned)bp;
    unsigned th = (unsigned)__builtin_amdgcn_update_dpp(0, (int)h, CTRL, 0xF, 0xF, true);
    unsigned tl = (unsigned)__builtin_amdgcn_update_dpp(0, (int)l, CTRL, 0xF, 0xF, true);
    unsigned long long tp = ((unsigned long long)th << 32) | tl;
    bp = tp > bp ? tp : bp;
}
// after these 6 steps lane 63 holds the wave max
#define DPP_REDUCE2(bp) dpp2<0x111>(bp); dpp2<0x112>(bp); dpp2<0x114>(bp); \
    dpp2<0x118>(bp); dpp2<0x142>(bp); dpp2<0x143>(bp);

#define FPS_DECL(i) v2f px##i, py##i, pz##i, ds##i;
#define FPS_LOAD(i) { int g0 = tid + (2*(i))*T, g1 = g0 + T; \
    px##i = (v2f){X[g0], X[g1]}; py##i = (v2f){X[N+g0], X[N+g1]}; \
    pz##i = (v2f){X[2*N+g0], X[2*N+g1]}; ds##i = (v2f){1e10f, 1e10f}; }
#define FPS_PIN(i) asm volatile("" : "+v"(px##i), "+v"(py##i), "+v"(pz##i));
// dist >= 0 => float bit order == value order; ~gi larger => gi smaller, so
// u64 max == (dist >, tie: idx <) exactly. Slot pairing doesn't affect the max.
#define FPS_UPD(i) { \
    v2f dx = px##i - l2x, dy = py##i - l2y, dz = pz##i - l2z; \
    v2f dd = __builtin_elementwise_fma(dz, dz, __builtin_elementwise_fma(dy, dy, dx*dx)); \
    float n0 = fminf(ds##i.x, dd.x), n1 = fminf(ds##i.y, dd.y); \
    ds##i = (v2f){n0, n1}; \
    unsigned long long c0 = ((unsigned long long)__float_as_uint(n0) << 32) | (unsigned)~(tid + (2*(i))*T); \
    unsigned long long c1 = ((unsigned long long)__float_as_uint(n1) << 32) | (unsigned)~(tid + (2*(i)+1)*T); \
    bp = c0 > bp ? c0 : bp; bp = c1 > bp ? c1 : bp; }

#define RPT8(M) M(0) M(1) M(2) M(3) M(4) M(5) M(6) M(7)
#define RPT2(M) M(0) M(1)

// multi-wave (T threads, NW waves): one barrier/iter, u64 keys combined via LDS
#define FPS_MW(RPT, N_P, NP_P, T_P, NW) \
    constexpr int N = N_P, NPOINT = NP_P, T = T_P; \
    const int b = blockIdx.x; \
    const float* X = xyz + (size_t)b * 3 * N; \
    float* NX = nxyz + (size_t)b * 3 * NPOINT; \
    int tid = threadIdx.x; \
    RPT(FPS_DECL) RPT(FPS_LOAD) RPT(FPS_PIN) \
    __shared__ float4 sxyz[N]; \
    __shared__ unsigned long long sred[2][NW]; \
    for (int t = tid; t < N; t += T) \
        sxyz[t] = make_float4(X[t], X[N+t], X[2*N+t], 0.f); \
    if (tid == 0){ sidx[(size_t)b * NPOINT] = 0; \
        NX[0] = X[0]; NX[NPOINT] = X[N]; NX[2*NPOINT] = X[2*N]; } \
    v2f l2x = (v2f){X[0], X[0]}, l2y = (v2f){X[N], X[N]}, l2z = (v2f){X[2*N], X[2*N]}; \
    __syncthreads(); \
    for (int i = 1; i < NPOINT; ++i){ \
        unsigned long long bp = 0; \
        RPT(FPS_UPD) \
        DPP_REDUCE2(bp) \
        int buf = i & 1; \
        if ((tid & 63) == 63) sred[buf][tid >> 6] = bp; \
        __syncthreads(); \
        unsigned long long pp = sred[buf][0]; \
        _Pragma("unroll") \
        for (int k = 1; k < NW; ++k){ unsigned long long pk = sred[buf][k]; pp = pk > pp ? pk : pp; } \
        int i0 = (int)~(unsigned)pp; \
        float4 wn = sxyz[i0]; \
        l2x = (v2f){wn.x, wn.x}; l2y = (v2f){wn.y, wn.y}; l2z = (v2f){wn.z, wn.z}; \
        if (tid == 0){ sidx[(size_t)b * NPOINT + i] = i0; \
            NX[i] = wn.x; NX[NPOINT + i] = wn.y; NX[2*NPOINT + i] = wn.z; } \
    }

// single-wave (64 threads): no barrier, readlane broadcast of key low word
#define FPS_SW(RPT, N_P, NP_P) \
    constexpr int N = N_P, NPOINT = NP_P, T = 64; \
    const int b = blockIdx.x; \
    const float* X = xyz + (size_t)b * 3 * N; \
    float* NX = nxyz + (size_t)b * 3 * NPOINT; \
    int tid = threadIdx.x; \
    RPT(FPS_DECL) RPT(FPS_LOAD) RPT(FPS_PIN) \
    __shared__ float4 sxyz[N]; \
    for (int t = tid; t < N; t += T) \
        sxyz[t] = make_float4(X[t], X[N+t], X[2*N+t], 0.f); \
    if (tid == 0){ sidx[(size_t)b * NPOINT] = 0; \
        NX[0] = X[0]; NX[NPOINT] = X[N]; NX[2*NPOINT] = X[2*N]; } \
    v2f l2x = (v2f){X[0], X[0]}, l2y = (v2f){X[N], X[N]}, l2z = (v2f){X[2*N], X[2*N]}; \
    for (int i = 1; i < NPOINT; ++i){ \
        unsigned long long bp = 0; \
        RPT(FPS_UPD) \
        DPP_REDUCE2(bp) \
        int i0 = (int)~(unsigned)__builtin_amdgcn_readlane((int)(unsigned)bp, 63); \
        float4 wn = sxyz[i0]; \
        l2x = (v2f){wn.x, wn.x}; l2y = (v2f){wn.y, wn.y}; l2z = (v2f){wn.z, wn.z}; \
        if (tid == 0){ sidx[(size_t)b * NPOINT + i] = i0; \
            NX[i] = wn.x; NX[NPOINT + i] = wn.y; NX[2*NPOINT + i] = wn.z; } \
    }

__global__ void __launch_bounds__(256, 1)
k_fps16(const float* __restrict__ xyz, int* __restrict__ sidx, float* __restrict__ nxyz){
    FPS_MW(RPT8, 4096, 1024, 256, 4)
}
__global__ void __launch_bounds__(64, 1)
k_fps4(const float* __restrict__ xyz, int* __restrict__ sidx, float* __restrict__ nxyz){
    FPS_SW(RPT8, 1024, 256)
}
__global__ void __launch_bounds__(64, 1)
k_fps1(const float* __restrict__ xyz, int* __restrict__ sidx, float* __restrict__ nxyz){
    FPS_SW(RPT2, 256, 64)
}

// ---------------- neighbor sum of leaky, point-major input (wave per column) ----------------
__global__ void __launch_bounds__(256, 1)
k_gather_sum_pm(const float* __restrict__ pm, const int* __restrict__ idx,
                float* __restrict__ out, int n){
    __shared__ float tile[64][65];
    int b = blockIdx.y;
    int j0 = blockIdx.x * 64;
    int lane = threadIdx.x & 63;
    int w = threadIdx.x >> 6;
    const float* PM = pm + (size_t)b * n * 64;
    const int* ID = idx + ((size_t)b * n + j0) * 8;
    for (int c = 0; c < 16; ++c){
        int jl = w * 16 + c;
        const int* id = ID + jl * 8;
        float v = 0.f;
        #pragma unroll
        for (int k = 0; k < 8; ++k)
            v += leaky(PM[(size_t)id[k] * 64 + lane]);
        tile[jl][lane] = v;
    }
    __syncthreads();
    float* O = out + (size_t)b * 64 * n + j0;
    for (int c = 0; c < 16; ++c){
        int d = w * 16 + c;
        O[(size_t)d * n + lane] = tile[lane][d];
    }
}

// ---------------- max-pool over k neighbors, point-major in, dual-write out ----------------
__global__ void __launch_bounds__(256, 1)
k_pool_max_pm(const float* __restrict__ pm, const int* __restrict__ idx,
              float* __restrict__ out, float* __restrict__ pmo, int np, int nsrc){
    __shared__ float tile[64][65];
    int b = blockIdx.y;
    int m0 = blockIdx.x * 64;
    int lane = threadIdx.x & 63;
    int w = threadIdx.x >> 6;
    const float* PM = pm + (size_t)b * nsrc * 64;
    float* PMO = pmo + (size_t)b * np * 64;
    const int* ID = idx + ((size_t)b * np + m0) * 8;
    for (int c = 0; c < 16; ++c){
        int ml = w * 16 + c;
        const int* id = ID + ml * 8;
        float v = -FLT_MAX;
        #pragma unroll
        for (int k = 0; k < 8; ++k)
            v = fmaxf(v, PM[(size_t)id[k] * 64 + lane]);
        tile[ml][lane] = v;
        PMO[(size_t)(m0 + ml) * 64 + lane] = v;   // coalesced pm write
    }
    __syncthreads();
    float* O = out + (size_t)b * 64 * np + m0;
    for (int c = 0; c < 16; ++c){
        int d = w * 16 + c;
        O[(size_t)d * np + lane] = tile[lane][d];
    }
}

// ---------------- dual GEMM + epilogue, dual-write dm+pm ----------------
#define RPT16(M) M(0) M(1) M(2) M(3) M(4) M(5) M(6) M(7) \
                 M(8) M(9) M(10) M(11) M(12) M(13) M(14) M(15)
#define RC_DECL(i) float a##i = 0.f;
#define RC_FMA(i)  a##i = fmaf(wc[i], h, fmaf(wg[i], sv, a##i));
#define RC_FIN(i)  a##i = a##i * inv + Pr[(size_t)(i) * n];
#define RC_ST(i)   O[(size_t)(i) * n] = a##i;
#define RC_STPM(i) PO[i] = a##i;

__global__ void __launch_bounds__(256, 1)
k_res_conv(const float* __restrict__ pts, const float* __restrict__ s,
           const float* __restrict__ wcT, const float* __restrict__ wgT,
           float* __restrict__ out, float* __restrict__ pmo, int n){
    int j = blockIdx.x * 64 + threadIdx.x;   // column
    int g = threadIdx.y;                     // output group (wave-uniform)
    if (j >= n) return;
    int b = blockIdx.y;
    const float* P = pts + (size_t)b * 64 * n + j;
    const float* S = s   + (size_t)b * 64 * n + j;
    RPT16(RC_DECL)
    for (int d = 0; d < 64; ++d){
        float h  = leaky(P[(size_t)d * n]);
        float sv = S[(size_t)d * n];
        const float* wc = wcT + d * 64 + g * 16;  // wave-uniform -> s_load
        const float* wg = wgT + d * 64 + g * 16;
        RPT16(RC_FMA)
    }
    const float inv = 1.0f / 9.0f;
    const float* Pr = P + (size_t)(g * 16) * n;
    RPT16(RC_FIN)
    float* O = out + ((size_t)b * 64 + g * 16) * n + j;
    RPT16(RC_ST)
    float* PO = pmo + ((size_t)b * n + j) * 64 + g * 16;   // fills one 64B sector
    RPT16(RC_STPM)
}

// ---------------- last layer: leaky -> 1x1 conv to 1 channel ----------------
__global__ void k_final(const float* __restrict__ pts, const float* __restrict__ wl,
                        float* __restrict__ out){
    int t = blockIdx.x * blockDim.x + threadIdx.x;
    if (t >= 512) return;
    int b = t >> 6, m = t & 63;
    const float* P = pts + (size_t)b * 64 * 64;
    float acc = 0.f;
    for (int d = 0; d < 64; ++d) acc += wl[d] * leaky(P[d * 64 + m]);
    out[t] = acc;
}

extern "C" void kernel_launch(void* const* d_in, const int* in_sizes, int n_in,
                              void* d_out, int out_size, void* d_ws, size_t ws_size,
                              hipStream_t stream){
    const float* xyz_in  = (const float*)d_in[0];
    const float* w0      = (const float*)d_in[1];
    const float* fn_wc   = (const float*)d_in[2];
    const float* fn_wg   = (const float*)d_in[3];
    const float* res_wc  = (const float*)d_in[4];
    const float* res_wg  = (const float*)d_in[5];
    const float* w_last  = (const float*)d_in[6];
    float* out = (float*)d_out;

    char* ws = (char*)d_ws;
    size_t off = 0;
    auto alloc = [&](size_t bytes) -> char* {
        char* p = ws + off;
        off = (off + bytes + 255) & ~(size_t)255;
        return p;
    };
    float* wT_fnc = (float*)alloc(2UL  * 4096 * 4);
    float* wT_fng = (float*)alloc(2UL  * 4096 * 4);
    float* wT_rc  = (float*)alloc(12UL * 4096 * 4);
    float* wT_rg  = (float*)alloc(12UL * 4096 * 4);
    float* pts_a  = (float*)alloc(8UL * 64 * 4096 * 4);
    float* pts_b  = (float*)alloc(8UL * 64 * 4096 * 4);
    float* s_buf  = (float*)alloc(8UL * 64 * 4096 * 4);
    float* pm_a   = (float*)alloc(8UL * 64 * 4096 * 4);
    float* pm_b   = (float*)alloc(8UL * 64 * 4096 * 4);
    int*   idx_b  = (int*)  alloc(8UL * 4096 * 8 * 4);
    float* xyz1   = (float*)alloc(8UL * 3 * 1024 * 4);
    float* xyz2   = (float*)alloc(8UL * 3 * 1024 * 4);
    int*   sidx   = (int*)  alloc(8UL * 1024 * 4);

    // transpose all weight matrices to [d][o]
    k_transpose<<<2,  256, 0, stream>>>(fn_wc,  wT_fnc);
    k_transpose<<<2,  256, 0, stream>>>(fn_wg,  wT_fng);
    k_transpose<<<12, 256, 0, stream>>>(res_wc, wT_rc);
    k_transpose<<<12, 256, 0, stream>>>(res_wg, wT_rg);

    int n = 4096;
    k_conv0<<<(8 * 64 * n) / 256, 256, 0, stream>>>(xyz_in, w0, pts_a, n);
    {
        dim3 tp(n / 64, 8);
        k_to_pm<<<tp, 256, 0, stream>>>(pts_a, pm_a, n);
    }

    const float* cxyz = xyz_in;
    {
        dim3 kb((n + BKNN - 1) / BKNN, 8);
        k_knn<<<kb, BKNN, 0, stream>>>(cxyz, cxyz, n, n, idx_b);
    }
    float* pc = pts_a; float* pn = pts_b;
    float* pmc = pm_a; float* pmn = pm_b;
    dim3 rcb(64, 4);
    for (int j = 0; j < 2; ++j){
        dim3 g(n / 64, 8);
        k_gather_sum_pm<<<g, 256, 0, stream>>>(pmc, idx_b, s_buf, n);
        k_res_conv<<<g, rcb, 0, stream>>>(pc, s_buf, wT_fnc + j * 4096, wT_fng + j * 4096,
                                          pn, pmn, n);
        float* t = pc; pc = pn; pn = t;
        t = pmc; pmc = pmn; pmn = t;
    }

    float* xyzbufs[2] = {xyz1, xyz2};
    for (int l = 0; l < 3; ++l){
        int np = n / 4;
        float* nxyz = xyzbufs[l & 1];
        if (n == 4096)      k_fps16<<<8, 256, 0, stream>>>(cxyz, sidx, nxyz);
        else if (n == 1024) k_fps4<<<8, 64, 0, stream>>>(cxyz, sidx, nxyz);
        else                k_fps1<<<8, 64, 0, stream>>>(cxyz, sidx, nxyz);

        dim3 kg((np + BKNN - 1) / BKNN, 8);
        k_knn<<<kg, BKNN, 0, stream>>>(nxyz, cxyz, np, n, idx_b);

        dim3 pp(np / 64, 8);
        k_pool_max_pm<<<pp, 256, 0, stream>>>(pmc, idx_b, pn, pmn, np, n);
        float* t = pc; pc = pn; pn = t;
        t = pmc; pmc = pmn; pmn = t;

        cxyz = nxyz; n = np;

        dim3 ks((n + BKNN - 1) / BKNN, 8);
        k_knn<<<ks, BKNN, 0, stream>>>(cxyz, cxyz, n, n, idx_b);

        for (int i = 0; i < 4; ++i){
            dim3 g(n / 64, 8);
            k_gather_sum_pm<<<g, 256, 0, stream>>>(pmc, idx_b, s_buf, n);
            k_res_conv<<<g, rcb, 0, stream>>>(pc, s_buf, wT_rc + (l * 4 + i) * 4096,
                                              wT_rg + (l * 4 + i) * 4096, pn, pmn, n);
            t = pc; pc = pn; pn = t;
            t = pmc; pmc = pmn; pmn = t;
        }
    }

    k_final<<<2, 256, 0, stream>>>(pc, w_last, out);
}

// Round 11
// 2236.399 us; speedup vs baseline: 1.2995x; 1.1657x over previous
//
#include <hip/hip_runtime.h>
#include <hip/hip_bf16.h>
#include <float.h>

#define NEG_SLOPE 0.01f

typedef float v2f __attribute__((ext_vector_type(2)));

__device__ __forceinline__ float leaky(float x){ return x >= 0.0f ? x : NEG_SLOPE * x; }

#if !__has_builtin(__builtin_elementwise_fma)
#error "need __builtin_elementwise_fma"
#endif

#define RPT16(M) M(0) M(1) M(2) M(3) M(4) M(5) M(6) M(7) \
                 M(8) M(9) M(10) M(11) M(12) M(13) M(14) M(15)
#define RPT8(M) M(0) M(1) M(2) M(3) M(4) M(5) M(6) M(7)
#define RPT2(M) M(0) M(1)

// ---------------- all 28 weight matrices [o][d] -> [d][o], one launch ----------------
// dst layout: [0,1]=fn_wc, [2,3]=fn_wg, [4..15]=res_wc, [16..27]=res_wg
__global__ void k_transpose_all(const float* __restrict__ a, const float* __restrict__ b2,
                                const float* __restrict__ c, const float* __restrict__ d,
                                float* __restrict__ dst){
    int m = blockIdx.x;
    const float* s;
    if (m < 2) s = a + (size_t)m * 4096;
    else if (m < 4) s = b2 + (size_t)(m - 2) * 4096;
    else if (m < 16) s = c + (size_t)(m - 4) * 4096;
    else s = d + (size_t)(m - 16) * 4096;
    float* o = dst + (size_t)m * 4096;
    for (int t = threadIdx.x; t < 4096; t += blockDim.x){
        int oo = t >> 6, dd = t & 63;
        o[dd * 64 + oo] = s[t];
    }
}

// ---------------- first conv 3->64, dual-write dm + pm ----------------
__global__ void __launch_bounds__(256, 1)
k_conv0(const float* __restrict__ xyz, const float* __restrict__ w0,
        float* __restrict__ dm, float* __restrict__ pm, int n){
    int b = blockIdx.y;
    int lane = threadIdx.x & 63;
    int w = threadIdx.x >> 6;
    int j = blockIdx.x * 64 + lane;
    const float* X = xyz + (size_t)b * 3 * n;
    float x = X[j], y = X[n + j], z = X[2 * n + j];
    float* PO = pm + ((size_t)b * n + j) * 64 + w * 16;
    #pragma unroll
    for (int c = 0; c < 16; ++c){
        int oo = w * 16 + c;
        float v = w0[oo*3] * x + w0[oo*3+1] * y + w0[oo*3+2] * z;
        dm[((size_t)b * 64 + oo) * n + j] = v;
        PO[c] = v;
    }
}

// ---------------- kNN: 256-thread blocks, 4x unrolled prefetched inner loop ----------------
#define KNN_CHUNK 1024
#define BKNN 256

#define KNN_INS(bdX, biX) { bool c = cd < bdX; float tf = bdX; int ti = biX; \
    bdX = c ? cd : bdX; biX = c ? ci : biX; cd = c ? tf : cd; ci = c ? ti : ci; }

#define KNN_PROC(r, jj) { \
    float dot = qx * r.x + qy * r.y + qz * r.z; \
    float dcur = qq + r.w - 2.0f * dot; \
    if (dcur < bd7){ \
        float cd = dcur; int ci = (jj); \
        KNN_INS(bd0, bi0); KNN_INS(bd1, bi1); KNN_INS(bd2, bi2); KNN_INS(bd3, bi3); \
        KNN_INS(bd4, bi4); KNN_INS(bd5, bi5); KNN_INS(bd6, bi6); KNN_INS(bd7, bi7); \
    } }

__global__ void __launch_bounds__(BKNN, 2)
k_knn(const float* __restrict__ q, const float* __restrict__ ref,
      int M, int Nr, int* __restrict__ idx_out){
    __shared__ float4 sref[KNN_CHUNK];
    int b = blockIdx.y;
    int m = blockIdx.x * BKNN + threadIdx.x;
    const float* Q = q + (size_t)b * 3 * M;
    const float* R = ref + (size_t)b * 3 * Nr;
    bool valid = (m < M);
    float qx = 0.f, qy = 0.f, qz = 0.f, qq = 0.f;
    if (valid){
        qx = Q[m]; qy = Q[M + m]; qz = Q[2 * M + m];
        qq = qx*qx + qy*qy + qz*qz;
    }
    float bd0 = FLT_MAX, bd1 = FLT_MAX, bd2 = FLT_MAX, bd3 = FLT_MAX;
    float bd4 = FLT_MAX, bd5 = FLT_MAX, bd6 = FLT_MAX, bd7 = FLT_MAX;
    int bi0 = 0, bi1 = 0, bi2 = 0, bi3 = 0, bi4 = 0, bi5 = 0, bi6 = 0, bi7 = 0;

    for (int base = 0; base < Nr; base += KNN_CHUNK){
        int jmax = min(KNN_CHUNK, Nr - base);
        for (int j = threadIdx.x; j < jmax; j += BKNN){
            float rx = R[base + j], ry = R[Nr + base + j], rz = R[2 * Nr + base + j];
            sref[j] = make_float4(rx, ry, rz, rx*rx + ry*ry + rz*rz);
        }
        __syncthreads();
        // jmax is always a multiple of 4 (1024/256/64)
        for (int j = 0; j < jmax; j += 4){
            float4 r0 = sref[j+0]; float4 r1 = sref[j+1];
            float4 r2 = sref[j+2]; float4 r3 = sref[j+3];
            KNN_PROC(r0, base + j + 0)
            KNN_PROC(r1, base + j + 1)
            KNN_PROC(r2, base + j + 2)
            KNN_PROC(r3, base + j + 3)
        }
        __syncthreads();
    }
    if (valid){
        int* o = idx_out + ((size_t)b * M + m) * 8;
        o[0] = bi0; o[1] = bi1; o[2] = bi2; o[3] = bi3;
        o[4] = bi4; o[5] = bi5; o[6] = bi6; o[7] = bi7;
    }
}

// ---------------- farthest point sampling (unchanged from r10) ----------------
template<int CTRL>
__device__ __forceinline__ void dpp2(unsigned long long &bp){
    unsigned h = (unsigned)(bp >> 32), l = (unsigned)bp;
    unsigned th = (unsigned)__builtin_amdgcn_update_dpp(0, (int)h, CTRL, 0xF, 0xF, true);
    unsigned tl = (unsigned)__builtin_amdgcn_update_dpp(0, (int)l, CTRL, 0xF, 0xF, true);
    unsigned long long tp = ((unsigned long long)th << 32) | tl;
    bp = tp > bp ? tp : bp;
}
#define DPP_REDUCE2(bp) dpp2<0x111>(bp); dpp2<0x112>(bp); dpp2<0x114>(bp); \
    dpp2<0x118>(bp); dpp2<0x142>(bp); dpp2<0x143>(bp);

#define FPS_DECL(i) v2f px##i, py##i, pz##i, ds##i;
#define FPS_LOAD(i) { int g0 = tid + (2*(i))*T, g1 = g0 + T; \
    px##i = (v2f){X[g0], X[g1]}; py##i = (v2f){X[N+g0], X[N+g1]}; \
    pz##i = (v2f){X[2*N+g0], X[2*N+g1]}; ds##i = (v2f){1e10f, 1e10f}; }
#define FPS_PIN(i) asm volatile("" : "+v"(px##i), "+v"(py##i), "+v"(pz##i));
// dist >= 0 => float bit order == value order; ~gi larger => gi smaller, so
// u64 max == (dist >, tie: idx <) exactly.
#define FPS_UPD(i) { \
    v2f dx = px##i - l2x, dy = py##i - l2y, dz = pz##i - l2z; \
    v2f dd = __builtin_elementwise_fma(dz, dz, __builtin_elementwise_fma(dy, dy, dx*dx)); \
    float n0 = fminf(ds##i.x, dd.x), n1 = fminf(ds##i.y, dd.y); \
    ds##i = (v2f){n0, n1}; \
    unsigned long long c0 = ((unsigned long long)__float_as_uint(n0) << 32) | (unsigned)~(tid + (2*(i))*T); \
    unsigned long long c1 = ((unsigned long long)__float_as_uint(n1) << 32) | (unsigned)~(tid + (2*(i)+1)*T); \
    bp = c0 > bp ? c0 : bp; bp = c1 > bp ? c1 : bp; }

#define FPS_MW(RPT, N_P, NP_P, T_P, NW) \
    constexpr int N = N_P, NPOINT = NP_P, T = T_P; \
    const int b = blockIdx.x; \
    const float* X = xyz + (size_t)b * 3 * N; \
    float* NX = nxyz + (size_t)b * 3 * NPOINT; \
    int tid = threadIdx.x; \
    RPT(FPS_DECL) RPT(FPS_LOAD) RPT(FPS_PIN) \
    __shared__ float4 sxyz[N]; \
    __shared__ unsigned long long sred[2][NW]; \
    for (int t = tid; t < N; t += T) \
        sxyz[t] = make_float4(X[t], X[N+t], X[2*N+t], 0.f); \
    if (tid == 0){ sidx[(size_t)b * NPOINT] = 0; \
        NX[0] = X[0]; NX[NPOINT] = X[N]; NX[2*NPOINT] = X[2*N]; } \
    v2f l2x = (v2f){X[0], X[0]}, l2y = (v2f){X[N], X[N]}, l2z = (v2f){X[2*N], X[2*N]}; \
    __syncthreads(); \
    for (int i = 1; i < NPOINT; ++i){ \
        unsigned long long bp = 0; \
        RPT(FPS_UPD) \
        DPP_REDUCE2(bp) \
        int buf = i & 1; \
        if ((tid & 63) == 63) sred[buf][tid >> 6] = bp; \
        __syncthreads(); \
        unsigned long long pp = sred[buf][0]; \
        _Pragma("unroll") \
        for (int k = 1; k < NW; ++k){ unsigned long long pk = sred[buf][k]; pp = pk > pp ? pk : pp; } \
        int i0 = (int)~(unsigned)pp; \
        float4 wn = sxyz[i0]; \
        l2x = (v2f){wn.x, wn.x}; l2y = (v2f){wn.y, wn.y}; l2z = (v2f){wn.z, wn.z}; \
        if (tid == 0){ sidx[(size_t)b * NPOINT + i] = i0; \
            NX[i] = wn.x; NX[NPOINT + i] = wn.y; NX[2*NPOINT + i] = wn.z; } \
    }

#define FPS_SW(RPT, N_P, NP_P) \
    constexpr int N = N_P, NPOINT = NP_P, T = 64; \
    const int b = blockIdx.x; \
    const float* X = xyz + (size_t)b * 3 * N; \
    float* NX = nxyz + (size_t)b * 3 * NPOINT; \
    int tid = threadIdx.x; \
    RPT(FPS_DECL) RPT(FPS_LOAD) RPT(FPS_PIN) \
    __shared__ float4 sxyz[N]; \
    for (int t = tid; t < N; t += T) \
        sxyz[t] = make_float4(X[t], X[N+t], X[2*N+t], 0.f); \
    if (tid == 0){ sidx[(size_t)b * NPOINT] = 0; \
        NX[0] = X[0]; NX[NPOINT] = X[N]; NX[2*NPOINT] = X[2*N]; } \
    v2f l2x = (v2f){X[0], X[0]}, l2y = (v2f){X[N], X[N]}, l2z = (v2f){X[2*N], X[2*N]}; \
    for (int i = 1; i < NPOINT; ++i){ \
        unsigned long long bp = 0; \
        RPT(FPS_UPD) \
        DPP_REDUCE2(bp) \
        int i0 = (int)~(unsigned)__builtin_amdgcn_readlane((int)(unsigned)bp, 63); \
        float4 wn = sxyz[i0]; \
        l2x = (v2f){wn.x, wn.x}; l2y = (v2f){wn.y, wn.y}; l2z = (v2f){wn.z, wn.z}; \
        if (tid == 0){ sidx[(size_t)b * NPOINT + i] = i0; \
            NX[i] = wn.x; NX[NPOINT + i] = wn.y; NX[2*NPOINT + i] = wn.z; } \
    }

__global__ void __launch_bounds__(256, 1)
k_fps16(const float* __restrict__ xyz, int* __restrict__ sidx, float* __restrict__ nxyz){
    FPS_MW(RPT8, 4096, 1024, 256, 4)
}
__global__ void __launch_bounds__(64, 1)
k_fps4(const float* __restrict__ xyz, int* __restrict__ sidx, float* __restrict__ nxyz){
    FPS_SW(RPT8, 1024, 256)
}
__global__ void __launch_bounds__(64, 1)
k_fps1(const float* __restrict__ xyz, int* __restrict__ sidx, float* __restrict__ nxyz){
    FPS_SW(RPT2, 256, 64)
}

// ---------------- max-pool over k neighbors, point-major in, dual-write out ----------------
__global__ void __launch_bounds__(256, 1)
k_pool_max_pm(const float* __restrict__ pm, const int* __restrict__ idx,
              float* __restrict__ out, float* __restrict__ pmo, int np, int nsrc){
    __shared__ float tile[64][65];
    int b = blockIdx.y;
    int m0 = blockIdx.x * 64;
    int lane = threadIdx.x & 63;
    int w = threadIdx.x >> 6;
    const float* PM = pm + (size_t)b * nsrc * 64;
    float* PMO = pmo + (size_t)b * np * 64;
    const int* ID = idx + ((size_t)b * np + m0) * 8;
    for (int c = 0; c < 16; ++c){
        int ml = w * 16 + c;
        const int* id = ID + ml * 8;
        float v = -FLT_MAX;
        #pragma unroll
        for (int k = 0; k < 8; ++k)
            v = fmaxf(v, PM[(size_t)id[k] * 64 + lane]);
        tile[ml][lane] = v;
        PMO[(size_t)(m0 + ml) * 64 + lane] = v;
    }
    __syncthreads();
    float* O = out + (size_t)b * 64 * np + m0;
    for (int c = 0; c < 16; ++c){
        int d = w * 16 + c;
        O[(size_t)d * np + lane] = tile[lane][d];
    }
}

// ---------------- FUSED gather_sum + dual GEMM + epilogue, dual-write dm+pm ----------------
// Phase 1: each wave gathers S (sum of leaky over 8 neighbors, pm-coalesced)
// for 16 of the block's 64 columns into the LDS tile. Phase 2: res_conv with
// sv read from LDS (tile[lane][d]: stride-65 rows -> conflict-free).
// Saves one kernel launch + the s_buf global round trip per res block.
#define RC_DECL(i) float a##i = 0.f;
#define RC_FMA(i)  a##i = fmaf(wc[i], h, fmaf(wg[i], sv, a##i));
#define RC_FIN(i)  a##i = a##i * inv + Pr[(size_t)(i) * n];
#define RC_ST(i)   O[(size_t)(i) * n] = a##i;
#define RC_STPM(i) PO[i] = a##i;

__global__ void __launch_bounds__(256, 1)
k_res_fused(const float* __restrict__ pts, const float* __restrict__ pm,
            const int* __restrict__ idx,
            const float* __restrict__ wcT, const float* __restrict__ wgT,
            float* __restrict__ out, float* __restrict__ pmo, int n){
    __shared__ float tile[64][65];
    int b = blockIdx.y;
    int j0 = blockIdx.x * 64;
    int lane = threadIdx.x & 63;
    int w = threadIdx.x >> 6;     // wave id == output group
    // phase 1: gather S
    const float* PM = pm + (size_t)b * n * 64;
    const int* ID = idx + ((size_t)b * n + j0) * 8;
    for (int c = 0; c < 16; ++c){
        int jl = w * 16 + c;
        const int* id = ID + jl * 8;   // wave-uniform -> s_load
        float v = 0.f;
        #pragma unroll
        for (int k = 0; k < 8; ++k)
            v += leaky(PM[(size_t)id[k] * 64 + lane]);
        tile[jl][lane] = v;
    }
    __syncthreads();
    // phase 2: dual GEMM; thread = column j0+lane, group w
    int j = j0 + lane;
    const float* P = pts + (size_t)b * 64 * n + j;
    const float* sc = &tile[lane][0];
    RPT16(RC_DECL)
    for (int d = 0; d < 64; ++d){
        float h  = leaky(P[(size_t)d * n]);
        float sv = sc[d];
        const float* wc = wcT + d * 64 + w * 16;   // wave-uniform -> s_load
        const float* wg = wgT + d * 64 + w * 16;
        RPT16(RC_FMA)
    }
    const float inv = 1.0f / 9.0f;
    const float* Pr = P + (size_t)(w * 16) * n;
    RPT16(RC_FIN)
    float* O = out + ((size_t)b * 64 + w * 16) * n + j;
    RPT16(RC_ST)
    float* PO = pmo + ((size_t)b * n + j) * 64 + w * 16;
    RPT16(RC_STPM)
}

// ---------------- last layer: leaky -> 1x1 conv to 1 channel ----------------
__global__ void k_final(const float* __restrict__ pts, const float* __restrict__ wl,
                        float* __restrict__ out){
    int t = blockIdx.x * blockDim.x + threadIdx.x;
    if (t >= 512) return;
    int b = t >> 6, m = t & 63;
    const float* P = pts + (size_t)b * 64 * 64;
    float acc = 0.f;
    for (int d = 0; d < 64; ++d) acc += wl[d] * leaky(P[d * 64 + m]);
    out[t] = acc;
}

extern "C" void kernel_launch(void* const* d_in, const int* in_sizes, int n_in,
                              void* d_out, int out_size, void* d_ws, size_t ws_size,
                              hipStream_t stream){
    const float* xyz_in  = (const float*)d_in[0];
    const float* w0      = (const float*)d_in[1];
    const float* fn_wc   = (const float*)d_in[2];
    const float* fn_wg   = (const float*)d_in[3];
    const float* res_wc  = (const float*)d_in[4];
    const float* res_wg  = (const float*)d_in[5];
    const float* w_last  = (const float*)d_in[6];
    float* out = (float*)d_out;

    char* ws = (char*)d_ws;
    size_t off = 0;
    auto alloc = [&](size_t bytes) -> char* {
        char* p = ws + off;
        off = (off + bytes + 255) & ~(size_t)255;
        return p;
    };
    float* wT_all = (float*)alloc(28UL * 4096 * 4);   // [fnc0,fnc1,fng0,fng1,rc*12,rg*12]
    float* pts_a  = (float*)alloc(8UL * 64 * 4096 * 4);
    float* pts_b  = (float*)alloc(8UL * 64 * 4096 * 4);
    float* pm_a   = (float*)alloc(8UL * 64 * 4096 * 4);
    float* pm_b   = (float*)alloc(8UL * 64 * 4096 * 4);
    int*   idx_b  = (int*)  alloc(8UL * 4096 * 8 * 4);
    float* xyz1   = (float*)alloc(8UL * 3 * 1024 * 4);
    float* xyz2   = (float*)alloc(8UL * 3 * 1024 * 4);
    int*   sidx   = (int*)  alloc(8UL * 1024 * 4);

    k_transpose_all<<<28, 256, 0, stream>>>(fn_wc, fn_wg, res_wc, res_wg, wT_all);

    int n = 4096;
    {
        dim3 g(n / 64, 8);
        k_conv0<<<g, 256, 0, stream>>>(xyz_in, w0, pts_a, pm_a, n);
    }

    const float* cxyz = xyz_in;
    {
        dim3 kb((n + BKNN - 1) / BKNN, 8);
        k_knn<<<kb, BKNN, 0, stream>>>(cxyz, cxyz, n, n, idx_b);
    }
    float* pc = pts_a; float* pn = pts_b;
    float* pmc = pm_a; float* pmn = pm_b;
    for (int j = 0; j < 2; ++j){
        dim3 g(n / 64, 8);
        k_res_fused<<<g, 256, 0, stream>>>(pc, pmc, idx_b, wT_all + j * 4096,
                                           wT_all + (2 + j) * 4096, pn, pmn, n);
        float* t = pc; pc = pn; pn = t;
        t = pmc; pmc = pmn; pmn = t;
    }

    float* xyzbufs[2] = {xyz1, xyz2};
    for (int l = 0; l < 3; ++l){
        int np = n / 4;
        float* nxyz = xyzbufs[l & 1];
        if (n == 4096)      k_fps16<<<8, 256, 0, stream>>>(cxyz, sidx, nxyz);
        else if (n == 1024) k_fps4<<<8, 64, 0, stream>>>(cxyz, sidx, nxyz);
        else                k_fps1<<<8, 64, 0, stream>>>(cxyz, sidx, nxyz);

        dim3 kg((np + BKNN - 1) / BKNN, 8);
        k_knn<<<kg, BKNN, 0, stream>>>(nxyz, cxyz, np, n, idx_b);

        dim3 pp(np / 64, 8);
        k_pool_max_pm<<<pp, 256, 0, stream>>>(pmc, idx_b, pn, pmn, np, n);
        float* t = pc; pc = pn; pn = t;
        t = pmc; pmc = pmn; pmn = t;

        cxyz = nxyz; n = np;

        dim3 ks((n + BKNN - 1) / BKNN, 8);
        k_knn<<<ks, BKNN, 0, stream>>>(cxyz, cxyz, n, n, idx_b);

        for (int i = 0; i < 4; ++i){
            dim3 g(n / 64, 8);
            k_res_fused<<<g, 256, 0, stream>>>(pc, pmc, idx_b,
                                               wT_all + (4 + l * 4 + i) * 4096,
                                               wT_all + (16 + l * 4 + i) * 4096, pn, pmn, n);
            t = pc; pc = pn; pn = t;
            t = pmc; pmc = pmn; pmn = t;
        }
    }

    k_final<<<2, 256, 0, stream>>>(pc, w_last, out);
}